// Round 4
// baseline (146.153 us; speedup 1.0000x reference)
//
#include <hip/hip_runtime.h>
#include <hip/hip_fp16.h>

typedef __fp16 h2_t __attribute__((ext_vector_type(2)));
typedef _Float16 f16x8 __attribute__((ext_vector_type(8)));
typedef float f32x4 __attribute__((ext_vector_type(4)));
typedef unsigned int uint32;

#define S_DIM 8192
#define B_DIM 8192
#define Q_DIM 64
#define A_DIM 1024
#define H_DIM 64
#define N_GATES 576

#define MT 64                  // rows per block (4 waves x 16)
#define KSPLIT 8
#define KC (S_DIM / KSPLIT)    // 1024 k per block
#define NCHUNK 8
#define CHUNK (N_GATES / NCHUNK)   // 72

__device__ __forceinline__ uint32 pk_f16(float x, float y) {
    h2_t h = __builtin_amdgcn_cvt_pkrtz(x, y);
    return __builtin_bit_cast(uint32, h);
}

__device__ __forceinline__ f32x4 mfma16(uint4 a, uint4 b, f32x4 c) {
    return __builtin_amdgcn_mfma_f32_16x16x32_f16(
        __builtin_bit_cast(f16x8, a), __builtin_bit_cast(f16x8, b), c, 0, 0, 0);
}

// Pack enc_w [64][8192] f32 -> MFMA B-fragment order f16:
// bpack[(kt*4 + nt)*64 + lane] = B[n = nt*16 + lane%16][k = kt*32 + (lane/16)*8 .. +8]
__global__ void k_packB(const float* __restrict__ encw, uint4* __restrict__ bpack) {
    const int gid  = blockIdx.x * 256 + threadIdx.x;   // 65536 total
    const int lane = gid & 63;
    const int nt   = (gid >> 6) & 3;
    const int kt   = gid >> 8;                          // 0..255
    const int n = nt * 16 + (lane & 15);
    const int k = kt * 32 + (lane >> 4) * 8;
    const float* p = encw + (size_t)n * S_DIM + k;
    float4 x0 = *(const float4*)p;
    float4 x1 = *(const float4*)(p + 4);
    uint4 r;
    r.x = pk_f16(x0.x, x0.y);
    r.y = pk_f16(x0.z, x0.w);
    r.z = pk_f16(x1.x, x1.y);
    r.w = pk_f16(x1.z, x1.w);
    bpack[gid] = r;
}

// K1: partial[ks][m][n] = state[m, ks-range] . enc_w[n, ks-range]
// Barrier-free: per-lane A fragments straight from global, f16 MFMA.
__global__ __launch_bounds__(256, 4) void k_gemm(
        const float* __restrict__ state, const uint4* __restrict__ bpack,
        float* __restrict__ partial) {
    const int t  = threadIdx.x;
    const int w  = t >> 6;          // wave -> m-subtile
    const int l  = t & 63;
    const int m0 = blockIdx.x * MT;
    const int ks = blockIdx.y;
    const int k0 = ks * KC;

    // A fragment coords (validated on HW in round 3): row = lane&15, k-group = lane>>4
    const int row = m0 + w * 16 + (l & 15);
    const int kg  = (l >> 4) * 8;
    const float* pa = state + (size_t)row * S_DIM + k0 + kg;
    const uint4* pb = bpack + (size_t)(k0 >> 5) * 4 * 64 + l;

    f32x4 acc[4] = {};

#pragma unroll 2
    for (int s = 0; s < KC / 32; ++s) {
        float4 a0 = *(const float4*)(pa + s * 32);
        float4 a1 = *(const float4*)(pa + s * 32 + 4);
        uint4 bf0 = pb[(size_t)(s * 4 + 0) * 64];
        uint4 bf1 = pb[(size_t)(s * 4 + 1) * 64];
        uint4 bf2 = pb[(size_t)(s * 4 + 2) * 64];
        uint4 bf3 = pb[(size_t)(s * 4 + 3) * 64];
        uint4 af;
        af.x = pk_f16(a0.x, a0.y);
        af.y = pk_f16(a0.z, a0.w);
        af.z = pk_f16(a1.x, a1.y);
        af.w = pk_f16(a1.z, a1.w);
        acc[0] = mfma16(af, bf0, acc[0]);
        acc[1] = mfma16(af, bf1, acc[1]);
        acc[2] = mfma16(af, bf2, acc[2]);
        acc[3] = mfma16(af, bf3, acc[3]);
    }

    // C/D: col = lane&15, row = (lane>>4)*4 + reg  (verified mapping)
    float* pc = partial + (size_t)ks * (B_DIM * Q_DIM);
    const int mr = m0 + w * 16 + (l >> 4) * 4;
    const int nc = l & 15;
#pragma unroll
    for (int nt = 0; nt < 4; ++nt)
#pragma unroll
        for (int r = 0; r < 4; ++r)
            pc[(size_t)(mr + r) * Q_DIM + nt * 16 + nc] = acc[nt][r];
}

// K2: x[r][q] = sum_ks partial + bias; softmax over q; per-block column sums
__global__ void k_softmax(const float* __restrict__ partial,
                          const float* __restrict__ encb,
                          float* __restrict__ colsum_parts) {
    __shared__ float red[4][64];
    const int lane = threadIdx.x & 63;
    const int wv   = threadIdx.x >> 6;
    const float eb = encb[lane];
    float accq = 0.f;
    for (int i = 0; i < 8; ++i) {
        const int r = blockIdx.x * 32 + i * 4 + wv;
        float x = eb;
#pragma unroll
        for (int ks = 0; ks < KSPLIT; ++ks)
            x += partial[(size_t)ks * (B_DIM * Q_DIM) + (size_t)r * Q_DIM + lane];
        float m = x;
        for (int o = 32; o > 0; o >>= 1) m = fmaxf(m, __shfl_xor(m, o));
        float e = __expf(x - m);
        float s = e;
        for (int o = 32; o > 0; o >>= 1) s += __shfl_xor(s, o);
        accq += e / s;
    }
    red[wv][lane] = accq;
    __syncthreads();
    if (threadIdx.x < 64) {
        colsum_parts[blockIdx.x * 64 + lane] =
            red[0][lane] + red[1][lane] + red[2][lane] + red[3][lane];
    }
}

// K3: fused tail — colsum reduce, gates (chunked polynomial + conv tree),
// measurements, hidden, output. One block, 1024 threads.
__global__ void k_tail(const float* __restrict__ colsum_parts,
                       const float* __restrict__ qp,
                       const float* __restrict__ mo,
                       const float* __restrict__ w1, const float* __restrict__ b1,
                       const float* __restrict__ w2, const float* __restrict__ b2,
                       float* __restrict__ out) {
    __shared__ float t0[64];
    __shared__ float tv[64];
    __shared__ float pA[8][64];
    __shared__ float pB[4][64];
    __shared__ float cs[N_GATES], ss[N_GATES];
    __shared__ float meas[A_DIM];        // also used as colsum scratch first
    __shared__ float hvec[64];
    const int t    = threadIdx.x;
    const int lane = t & 63;
    const int wv   = t >> 6;             // 0..15

    // trig tables
    if (t < N_GATES) {
        float th = qp[t] * 0.5f;
        cs[t] = __cosf(th);
        ss[t] = __sinf(th);
    }
    // colsum partial reduce: 256 blocks x 64 cols -> 16 groups
    {
        float c = 0.f;
#pragma unroll
        for (int i = 0; i < 16; ++i)
            c += colsum_parts[(wv + i * 16) * 64 + lane];
        meas[wv * 64 + lane] = c;
    }
    __syncthreads();
    if (t < 64) {
        float s = 0.f;
#pragma unroll
        for (int g = 0; g < 16; ++g) s += meas[g * 64 + t];
        t0[t] = s;
    }
    __syncthreads();

    // chunk polynomials: wave c computes P_c = prod_{g in chunk} (c_g + s_g x) mod x^64-1
    if (wv < NCHUNK) {
        float p = (lane == 0) ? 1.f : 0.f;
        const int g0 = wv * CHUNK;
        for (int g = 0; g < CHUNK; ++g) {
            float prev = __shfl(p, (lane + 63) & 63);
            p = fmaf(cs[g0 + g], p, ss[g0 + g] * prev);
        }
        pA[wv][lane] = p;
    }
    __syncthreads();
    // conv tree: 8 -> 4
    if (wv < 4) {
        float r = 0.f;
        for (int i = 0; i < 64; ++i)
            r += pA[2 * wv][i] * pA[2 * wv + 1][(lane - i) & 63];
        pB[wv][lane] = r;
    }
    __syncthreads();
    // 4 -> 2
    if (wv < 2) {
        float r = 0.f;
        for (int i = 0; i < 64; ++i)
            r += pB[2 * wv][i] * pB[2 * wv + 1][(lane - i) & 63];
        pA[wv][lane] = r;
    }
    __syncthreads();
    // 2 -> 1
    if (wv == 0) {
        float r = 0.f;
        for (int i = 0; i < 64; ++i)
            r += pA[0][i] * pA[1][(lane - i) & 63];
        pB[0][lane] = r;
    }
    __syncthreads();
    // apply to t0: tv[q] = sum_i f[i] * t0[(q-i)&63]
    if (wv == 0) {
        float r = 0.f;
        for (int i = 0; i < 64; ++i)
            r += pB[0][i] * t0[(lane - i) & 63];
        tv[lane] = r;
    }
    __syncthreads();

    // measurements: meas[a] = sum_q tv[q] * mo[a][q][0]
    {
        const float4* mo4 = (const float4*)(mo + (size_t)t * 128);
        float v = 0.f;
#pragma unroll
        for (int i = 0; i < 32; ++i) {
            float4 m4 = mo4[i];
            v = fmaf(tv[2 * i], m4.x, v);
            v = fmaf(tv[2 * i + 1], m4.z, v);
        }
        meas[t] = v;
    }
    __syncthreads();

    // hidden: 16 threads per j
    {
        const int j    = t >> 4;
        const int part = t & 15;
        const float4* w14 = (const float4*)(w1 + (size_t)j * A_DIM + part * 64);
        const float4* m4  = (const float4*)(meas + part * 64);
        float v = 0.f;
#pragma unroll
        for (int i = 0; i < 16; ++i) {
            float4 a = w14[i];
            float4 b = m4[i];
            v += a.x * b.x + a.y * b.y + a.z * b.z + a.w * b.w;
        }
        for (int o = 8; o > 0; o >>= 1) v += __shfl_xor(v, o);
        if (part == 0) hvec[j] = fmaxf(v + b1[j], 0.f);
    }
    __syncthreads();

    // output: out[a] = sum_j hvec[j] * w2[a][j] + b2[a]
    {
        const float4* w24 = (const float4*)(w2 + (size_t)t * H_DIM);
        float v = 0.f;
#pragma unroll
        for (int i = 0; i < 16; ++i) {
            float4 a = w24[i];
            v += a.x * hvec[4 * i] + a.y * hvec[4 * i + 1] +
                 a.z * hvec[4 * i + 2] + a.w * hvec[4 * i + 3];
        }
        out[t] = v + b2[t];
    }
}

extern "C" void kernel_launch(void* const* d_in, const int* in_sizes, int n_in,
                              void* d_out, int out_size, void* d_ws, size_t ws_size,
                              hipStream_t stream) {
    const float* state = (const float*)d_in[0];
    const float* encw  = (const float*)d_in[1];
    const float* encb  = (const float*)d_in[2];
    const float* qp    = (const float*)d_in[3];
    const float* mo    = (const float*)d_in[4];
    const float* w1    = (const float*)d_in[5];
    const float* b1    = (const float*)d_in[6];
    const float* w2    = (const float*)d_in[7];
    const float* b2    = (const float*)d_in[8];
    float* out = (float*)d_out;

    float* ws           = (float*)d_ws;
    float* colsum_parts = ws;                        // 256*64 = 16384 floats
    float* partial      = ws + 16384;                // 8 * 8192*64 floats (16 MB)
    uint4* bpack        = (uint4*)(partial + (size_t)KSPLIT * B_DIM * Q_DIM);  // 1 MB

    k_packB<<<dim3(256), dim3(256), 0, stream>>>(encw, bpack);
    k_gemm<<<dim3(B_DIM / MT, KSPLIT), dim3(256), 0, stream>>>(state, bpack, partial);
    k_softmax<<<dim3(256), dim3(256), 0, stream>>>(partial, encb, colsum_parts);
    k_tail<<<dim3(1), dim3(1024), 0, stream>>>(colsum_parts, qp, mo, w1, b1, w2, b2, out);
}